// Round 7
// baseline (208.155 us; speedup 1.0000x reference)
//
#include <hip/hip_runtime.h>
#include <math.h>

#define N_NODES  2000000
#define DIM      128
#define N_GRAPHS 16384

#define GBLOCKS  4096                 // 4 waves/block -> one wave per graph
#define ZENT     GBLOCKS              // blkZ entries

typedef float v4f __attribute__((ext_vector_type(4)));

__device__ __forceinline__ int lower_bound(const int* __restrict__ batch, int target) {
    int lo = 0, hi = N_NODES;
    while (lo < hi) {                  // 21 wave-uniform broadcast steps
        const int mid = (lo + hi) >> 1;
        if (batch[mid] < target) lo = mid + 1; else hi = mid;
    }
    return lo;
}

// -------- Fused kernel: one wave per graph, zero atomics --------
// Wave g owns rows [lower_bound(g), lower_bound(g+1)) — graph-aligned, so
// its accumulator is private: finished sums are STORED (not atomicAdd'ed)
// straight to out[g]. No acc buffer, no memset. Empty graphs store zeros
// (out is poisoned by the harness).
// Inner loop: lanes 0-31 take row rr, lanes 32-63 rr+1 (1KB contiguous per
// wave-load), unroll 4, nontemporal (1GB single-use stream). Per row:
// float4 dot with W fragment, 5-step butterfly within each 32-half,
// e = exp(s+b) (direct exp: |s| <~ 13 for this data; e/Z ratio identical to
// max-subtracted softmax), register fma. Halves merged via xor-32 at the end.
__global__ __launch_bounds__(256, 8) void fused_kernel(const float* __restrict__ x,
                                                       const int* __restrict__ batch,
                                                       const float* __restrict__ W,
                                                       const float* __restrict__ b,
                                                       float* __restrict__ out,
                                                       float* __restrict__ blkZ) {
    const int tid  = threadIdx.x;
    const int lane = tid & 63;
    const int l32  = lane & 31;
    const int half = lane >> 5;
    const int g    = blockIdx.x * 4 + (tid >> 6);

    const v4f wf    = *((const v4f*)W + l32);
    const float bias = b[0];

    const int r0 = lower_bound(batch, g);
    const int r1 = lower_bound(batch, g + 1);

    float zacc = 0.f;
    v4f racc = {0.f, 0.f, 0.f, 0.f};

    #pragma unroll 4
    for (int rr = r0; rr < r1; rr += 2) {
        const int row = rr + half;
        if (row < r1) {
            const v4f xv = __builtin_nontemporal_load(
                (const v4f*)(x + (long)row * DIM) + l32);
            float sv = xv[0] * wf[0] + xv[1] * wf[1] + xv[2] * wf[2] + xv[3] * wf[3];
            #pragma unroll
            for (int m = 16; m >= 1; m >>= 1) sv += __shfl_xor(sv, m, 64);
            const float e = __expf(sv + bias);
            zacc += e;
            racc[0] = fmaf(xv[0], e, racc[0]);
            racc[1] = fmaf(xv[1], e, racc[1]);
            racc[2] = fmaf(xv[2], e, racc[2]);
            racc[3] = fmaf(xv[3], e, racc[3]);
        }
    }

    // merge the two halves; store unscaled sums (scale pass divides by Z)
    racc[0] += __shfl_xor(racc[0], 32, 64);
    racc[1] += __shfl_xor(racc[1], 32, 64);
    racc[2] += __shfl_xor(racc[2], 32, 64);
    racc[3] += __shfl_xor(racc[3], 32, 64);
    if (half == 0) {
        *((v4f*)(out + (long)g * DIM) + l32) = racc;
    }

    // Z: zacc identical within each 32-half; merge halves, then 4 waves via LDS
    zacc += __shfl_xor(zacc, 32, 64);
    __shared__ float sm[4];
    if (lane == 0) sm[tid >> 6] = zacc;
    __syncthreads();
    if (tid == 0) blkZ[blockIdx.x] = sm[0] + sm[1] + sm[2] + sm[3];
}

// -------- Scale: reduce blkZ (redundantly per block), out *= 1/Z in place --------
__global__ __launch_bounds__(256) void scale_kernel(float* __restrict__ out,
                                                    const float* __restrict__ blkZ) {
    __shared__ float sm[256];
    float v = 0.f;
    #pragma unroll
    for (int i = 0; i < ZENT / 256; ++i) v += blkZ[i * 256 + threadIdx.x];
    sm[threadIdx.x] = v;
    __syncthreads();
    #pragma unroll
    for (int st = 128; st >= 1; st >>= 1) {
        if (threadIdx.x < st) sm[threadIdx.x] += sm[threadIdx.x + st];
        __syncthreads();
    }
    const float invZ = 1.0f / sm[0];

    const int i = blockIdx.x * 256 + threadIdx.x;   // one float4 per thread
    v4f a = ((v4f*)out)[i];
    a[0] *= invZ; a[1] *= invZ; a[2] *= invZ; a[3] *= invZ;
    ((v4f*)out)[i] = a;
}

extern "C" void kernel_launch(void* const* d_in, const int* in_sizes, int n_in,
                              void* d_out, int out_size, void* d_ws, size_t ws_size,
                              hipStream_t stream) {
    const float* x     = (const float*)d_in[0];
    const int*   batch = (const int*)d_in[1];
    const float* W     = (const float*)d_in[2];
    const float* b     = (const float*)d_in[3];
    float* out = (float*)d_out;

    float* blkZ = (float*)d_ws;       // ZENT floats

    fused_kernel<<<GBLOCKS, 256, 0, stream>>>(x, batch, W, b, out, blkZ);

    const int sc_grid = (N_GRAPHS * DIM / 4) / 256;  // 2048 blocks
    scale_kernel<<<sc_grid, 256, 0, stream>>>(out, blkZ);
}

// Round 8
// 193.997 us; speedup vs baseline: 1.0730x; 1.0730x over previous
//
#include <hip/hip_runtime.h>
#include <math.h>

#define N_NODES  2000000
#define DIM      128
#define N_GRAPHS 16384

#define FBLOCKS  2048
#define WAVES    (FBLOCKS * 4)                      // 8192 waves
#define RPW      ((N_NODES + WAVES - 1) / WAVES)    // 245 rows per wave

typedef float v4f __attribute__((ext_vector_type(4)));

// -------- Fused kernel: single pass over x, segment-structured --------
// Each full wave owns rows [r0, r1) — EQUAL ranges (R7 lesson: balance beats
// atomic-traffic savings). batch is sorted -> few contiguous graph segments
// per range; binary-search each end over the wave's small window (~8 steps,
// wave-uniform, L1-hot). Per segment, split into:
//   BODY: (len & ~7) rows = exact 4x-unrolled pair-iterations with NO
//         predicates — 4 independent NT loads off one base with immediate
//         offsets, then per pair: float4 dot with W fragment, 5-step
//         butterfly (xor<32 stays in-half; half0 reduces row rr, half1 row
//         rr+1), e = exp(s+bias), 4 register fma.
//   TAIL: <=7 rows, predicated pair loop (same math).
// Direct exp (no max-subtract): |s| <~ 13 for this data; e/Z ratio is
// mathematically identical to max-subtracted softmax.
// One atomic flush per segment (halves merged via xor-32).
// __launch_bounds__(256,8): VGPR<=64 -> all 2048 blocks co-resident, no
// residency tail. NT loads keep the 1GB single-use x stream from evicting
// batch/acc lines.
__global__ __launch_bounds__(256, 8) void fused_kernel(const float* __restrict__ x,
                                                       const int* __restrict__ batch,
                                                       const float* __restrict__ W,
                                                       const float* __restrict__ b,
                                                       float* __restrict__ acc,
                                                       float* __restrict__ blkZ) {
    const int tid  = threadIdx.x;
    const int lane = tid & 63;
    const int l32  = lane & 31;
    const int half = lane >> 5;
    const int wave = blockIdx.x * 4 + (tid >> 6);

    const v4f wf    = *((const v4f*)W + l32);
    const float bias = b[0];

    const int r0 = wave * RPW;
    const int r1 = min(r0 + RPW, N_NODES);

    float zacc = 0.f;

    int r = r0;
    while (r < r1) {
        const int g = batch[r];
        // upper_bound(batch, g) within (r, r1) — wave-uniform broadcast loads
        int lo = r + 1, hi = r1;
        while (lo < hi) {
            const int mid = (lo + hi) >> 1;
            if (batch[mid] <= g) lo = mid + 1; else hi = mid;
        }
        const int end = lo;

        v4f racc = {0.f, 0.f, 0.f, 0.f};

        // ---- body: full 8-row chunks, no predicates ----
        const int nb  = (end - r) & ~7;
        const int rb1 = r + nb;
        for (int rb = r; rb < rb1; rb += 8) {
            const float* bp = x + (long)(rb + half) * DIM + l32 * 4;
            #pragma unroll
            for (int j = 0; j < 4; ++j) {
                const v4f xv = __builtin_nontemporal_load((const v4f*)(bp + j * 2 * DIM));
                float sv = xv[0] * wf[0] + xv[1] * wf[1] + xv[2] * wf[2] + xv[3] * wf[3];
                #pragma unroll
                for (int m = 16; m >= 1; m >>= 1) sv += __shfl_xor(sv, m, 64);
                const float e = __expf(sv + bias);
                zacc += e;
                racc[0] = fmaf(xv[0], e, racc[0]);
                racc[1] = fmaf(xv[1], e, racc[1]);
                racc[2] = fmaf(xv[2], e, racc[2]);
                racc[3] = fmaf(xv[3], e, racc[3]);
            }
        }

        // ---- tail: <=7 rows, predicated ----
        for (int rr = rb1; rr < end; rr += 2) {
            const int row = rr + half;
            if (row < end) {
                const v4f xv = __builtin_nontemporal_load(
                    (const v4f*)(x + (long)row * DIM) + l32);
                float sv = xv[0] * wf[0] + xv[1] * wf[1] + xv[2] * wf[2] + xv[3] * wf[3];
                #pragma unroll
                for (int m = 16; m >= 1; m >>= 1) sv += __shfl_xor(sv, m, 64);
                const float e = __expf(sv + bias);
                zacc += e;
                racc[0] = fmaf(xv[0], e, racc[0]);
                racc[1] = fmaf(xv[1], e, racc[1]);
                racc[2] = fmaf(xv[2], e, racc[2]);
                racc[3] = fmaf(xv[3], e, racc[3]);
            }
        }

        // merge the two halves (same graph g) and flush once per segment
        racc[0] += __shfl_xor(racc[0], 32, 64);
        racc[1] += __shfl_xor(racc[1], 32, 64);
        racc[2] += __shfl_xor(racc[2], 32, 64);
        racc[3] += __shfl_xor(racc[3], 32, 64);
        if (half == 0) {
            float* a = acc + (long)g * DIM + l32 * 4;
            atomicAdd(a + 0, racc[0]);
            atomicAdd(a + 1, racc[1]);
            atomicAdd(a + 2, racc[2]);
            atomicAdd(a + 3, racc[3]);
        }
        r = end;
    }

    // Z: zacc identical within each 32-half; merge halves, then 4 waves via LDS
    zacc += __shfl_xor(zacc, 32, 64);
    __shared__ float sm[4];
    if (lane == 0) sm[tid >> 6] = zacc;
    __syncthreads();
    if (tid == 0) blkZ[blockIdx.x] = sm[0] + sm[1] + sm[2] + sm[3];
}

// -------- Finalize: reduce blkZ (redundantly per block) + out = acc/Z --------
__global__ __launch_bounds__(256) void finalize_kernel(const float* __restrict__ acc,
                                                       const float* __restrict__ blkZ,
                                                       float* __restrict__ out) {
    __shared__ float sm[256];
    float v = 0.f;
    #pragma unroll
    for (int i = 0; i < FBLOCKS / 256; ++i) v += blkZ[i * 256 + threadIdx.x];
    sm[threadIdx.x] = v;
    __syncthreads();
    #pragma unroll
    for (int st = 128; st >= 1; st >>= 1) {
        if (threadIdx.x < st) sm[threadIdx.x] += sm[threadIdx.x + st];
        __syncthreads();
    }
    const float invZ = 1.0f / sm[0];

    const int i = blockIdx.x * 256 + threadIdx.x;   // one float4 per thread
    const v4f a = ((const v4f*)acc)[i];
    v4f o = a;
    o[0] *= invZ; o[1] *= invZ; o[2] *= invZ; o[3] *= invZ;
    ((v4f*)out)[i] = o;
}

extern "C" void kernel_launch(void* const* d_in, const int* in_sizes, int n_in,
                              void* d_out, int out_size, void* d_ws, size_t ws_size,
                              hipStream_t stream) {
    const float* x     = (const float*)d_in[0];
    const int*   batch = (const int*)d_in[1];
    const float* W     = (const float*)d_in[2];
    const float* b     = (const float*)d_in[3];
    float* out = (float*)d_out;

    // ws layout (floats): acc[16384*128] | blkZ[FBLOCKS]
    float* acc  = (float*)d_ws;
    float* blkZ = acc + (long)N_GRAPHS * DIM;

    hipMemsetAsync(acc, 0, (size_t)N_GRAPHS * DIM * sizeof(float), stream);

    fused_kernel<<<FBLOCKS, 256, 0, stream>>>(x, batch, W, b, acc, blkZ);

    const int fin_grid = (N_GRAPHS * DIM / 4) / 256;  // 2048 blocks
    finalize_kernel<<<fin_grid, 256, 0, stream>>>(acc, blkZ, out);
}